// Round 6
// baseline (194.089 us; speedup 1.0000x reference)
//
#include <hip/hip_runtime.h>

#define B_ 64
#define N_ 2048
#define J_ 32
#define D_ 128
#define NEG_SLOPE_ 0.2f

typedef __attribute__((ext_vector_type(4))) float f32x4;
typedef __attribute__((ext_vector_type(8))) __bf16 bf16x8;
typedef __attribute__((ext_vector_type(4))) __bf16 bf16x4;

#define ACT_NONE 0
#define ACT_ELU 1
#define ACT_LEAKY 2

template<int ACT>
__device__ __forceinline__ float apply_act(float v) {
    if constexpr (ACT == ACT_ELU)        return v > 0.f ? v : __expf(v) - 1.f;
    else if constexpr (ACT == ACT_LEAKY) return v >= 0.f ? v : NEG_SLOPE_ * v;
    else return v;
}

// read one bf16x8 fragment from swizzled row-major [row][128] storage
__device__ __forceinline__ bf16x8 frag_ld(const __bf16* src, int row, int kc) {
    return *(const bf16x8*)&src[row * D_ + ((kc ^ (row & 7)) << 3)];
}

// preload this wave's 64-col W^T panel (A-operand) into registers: 16 frags
__device__ __forceinline__ void load_wregs(const __bf16* __restrict__ wmat,
                                           int wcol, int ln, int lq, bf16x8 wr_[4][4]) {
#pragma unroll
    for (int ks = 0; ks < 4; ++ks)
#pragma unroll
        for (int mt = 0; mt < 4; ++mt)
            wr_[ks][mt] = frag_ld(wmat, wcol * 64 + mt * 16 + ln, ks * 4 + lq);
}

// swapped-operand GEMM: out[jr][ic] = sum_k x[jr][k] * WT[ic][k]
// A = WT panel (regs), B = x rows {jr0+ln, jr1+ln} from LDS (A-frag-style reads).
// D: lane holds out[row = jr? + (l&15)][cols ic = wcol*64 + mt*16 + lq*4 .. +3]
__device__ __forceinline__ void gemmT(const __bf16* xb, const bf16x8 wr_[4][4],
                                      int jr0, int jr1, int ln, int lq, f32x4 acc[4][2]) {
    const f32x4 z = {0.f, 0.f, 0.f, 0.f};
#pragma unroll
    for (int mt = 0; mt < 4; ++mt) { acc[mt][0] = z; acc[mt][1] = z; }
#pragma unroll
    for (int ks = 0; ks < 4; ++ks) {
        const int kc = ks * 4 + lq;
        const bf16x8 b0 = frag_ld(xb, jr0 + ln, kc);
        const bf16x8 b1 = frag_ld(xb, jr1 + ln, kc);
#pragma unroll
        for (int mt = 0; mt < 4; ++mt) {
            acc[mt][0] = __builtin_amdgcn_mfma_f32_16x16x32_bf16(wr_[ks][mt], b0, acc[mt][0], 0, 0, 0);
            acc[mt][1] = __builtin_amdgcn_mfma_f32_16x16x32_bf16(wr_[ks][mt], b1, acc[mt][1], 0, 0, 0);
        }
    }
}

// swapped-GEMM epilogue: act(acc + bias) -> swizzled LDS rows, 4 bf16 (b64) per store
template<int ACT>
__device__ __forceinline__ void epiT_lds(const f32x4 acc[4][2], __bf16* dst,
                                         const float* __restrict__ bias,
                                         int wcol, int jr0, int jr1, int ln, int lq) {
#pragma unroll
    for (int mt = 0; mt < 4; ++mt) {
        const int cb = wcol * 64 + mt * 16 + lq * 4;
        const f32x4 bv = *(const f32x4*)&bias[cb];
#pragma unroll
        for (int nt = 0; nt < 2; ++nt) {
            const int jr = (nt ? jr1 : jr0) + ln;
            bf16x4 o;
#pragma unroll
            for (int r = 0; r < 4; ++r)
                o[r] = (__bf16)apply_act<ACT>(acc[mt][nt][r] + bv[r]);
            *(bf16x4*)&dst[jr * D_ + (((cb >> 3) ^ (jr & 7)) << 3) + (cb & 7)] = o;
        }
    }
}

// ---------- legacy standard-orientation core (k_head only) ----------
struct TCtx { int wr, wc, ln, lq; };

__device__ __forceinline__ void mfma_gemm(const __bf16* __restrict__ xb,
                                          const __bf16* __restrict__ wb,
                                          const TCtx& c, f32x4 acc[2][4]) {
    const f32x4 zero = {0.f, 0.f, 0.f, 0.f};
#pragma unroll
    for (int m = 0; m < 2; ++m)
#pragma unroll
        for (int n = 0; n < 4; ++n) acc[m][n] = zero;
    const int r0 = c.wr * 32 + c.ln;
    const int r1 = r0 + 16;
#pragma unroll
    for (int ks = 0; ks < 4; ++ks) {
        const int kc = ks * 4 + c.lq;
        const bf16x8 a0 = frag_ld(xb, r0, kc);
        const bf16x8 a1 = frag_ld(xb, r1, kc);
#pragma unroll
        for (int n = 0; n < 4; ++n) {
            const int nr = c.wc * 64 + n * 16 + c.ln;
            const bf16x8 bv = frag_ld(wb, nr, kc);
            acc[0][n] = __builtin_amdgcn_mfma_f32_16x16x32_bf16(a0, bv, acc[0][n], 0, 0, 0);
            acc[1][n] = __builtin_amdgcn_mfma_f32_16x16x32_bf16(a1, bv, acc[1][n], 0, 0, 0);
        }
    }
}

template<int ACT>
__device__ __forceinline__ void epi_lds(const f32x4 acc[2][4], __bf16* dst,
                                        const float* __restrict__ bias, float bscale,
                                        const TCtx& c) {
#pragma unroll
    for (int n = 0; n < 4; ++n) {
        const int gcol = c.wc * 64 + n * 16 + c.ln;
        const float bb = bscale * bias[gcol];
        const int cc = gcol >> 3, co = gcol & 7;
#pragma unroll
        for (int m = 0; m < 2; ++m) {
#pragma unroll
            for (int rg = 0; rg < 4; ++rg) {
                const int grow = c.wr * 32 + m * 16 + c.lq * 4 + rg;
                dst[grow * D_ + ((cc ^ (grow & 7)) << 3) + co] =
                    (__bf16)apply_act<ACT>(acc[m][n][rg] + bb);
            }
        }
    }
}

// merged prep: blocks 0-5 convert W fp32 -> WT bf16 swizzled; blocks 6-69 per-batch prep
__global__ __launch_bounds__(256) void k_prep(
    const float* __restrict__ w0, const float* __restrict__ w1,
    const float* __restrict__ w2, const float* __restrict__ w3,
    const float* __restrict__ w4, const float* __restrict__ w5,
    __bf16* __restrict__ wdst,
    const float* __restrict__ F, const int* __restrict__ STEP,
    const int* __restrict__ ENDB, const int* __restrict__ BIDX,
    float* __restrict__ Sbuf, int* __restrict__ nvalid, int* __restrict__ cnt_upd,
    unsigned short* __restrict__ lupd, unsigned char* __restrict__ flag,
    int* __restrict__ qcnt, int* __restrict__ queue) {
    const int t = threadIdx.x;
    if (blockIdx.x < 6) {
        const float* src;
        switch (blockIdx.x) {
            case 0: src = w0; break; case 1: src = w1; break; case 2: src = w2; break;
            case 3: src = w3; break; case 4: src = w4; break; default: src = w5; break;
        }
        __bf16* d = wdst + (size_t)blockIdx.x * D_ * D_;
        for (int id = t; id < D_ * 16; id += 256) {
            const int n = id >> 4, ch = id & 15;
            bf16x8 u;
#pragma unroll
            for (int j = 0; j < 8; ++j) u[j] = (__bf16)src[(ch * 8 + j) * D_ + n];
            *(bf16x8*)&d[n * D_ + ((ch ^ (n & 7)) << 3)] = u;
        }
        return;
    }
    const int b = blockIdx.x - 6;
    __shared__ int steps_s[J_];
    __shared__ int valid_s[J_];
    __shared__ int cu, nv, qbase;
    const int bi = BIDX[b];
    if (t == 0) { cu = 0; nv = 0; }
    __syncthreads();
    if (t < J_) {
        const int s = STEP[bi * J_ + t];
        const int e = ENDB[bi * J_ + t];
        steps_s[t] = s;
        const int v = (s <= e) ? 1 : 0;
        valid_s[t] = v;
        if (v) atomicAdd(&nv, 1);
    }
    __syncthreads();
    if (t < D_) {
        float acc = 0.f;
        for (int j = 0; j < J_; ++j)
            if (valid_s[j]) acc += F[((size_t)b * N_ + steps_s[j]) * D_ + t];
        Sbuf[b * D_ + t] = acc;
    }
    for (int i = t; i < N_; i += blockDim.x) {
        const bool head = (i < J_) && valid_s[i];
        unsigned char fl = 0;
        if (head) {
            fl = 1;
        } else if (i > steps_s[i >> 6]) {
            const int s = atomicAdd(&cu, 1);
            lupd[b * N_ + s] = (unsigned short)i;
            fl = 1;
        }
        flag[b * N_ + i] = fl;
    }
    __syncthreads();
    const int ntile = (cu + 31) >> 5;          // 32-row tiles
    if (t == 0) {
        nvalid[b] = nv;
        cnt_upd[b] = cu;
        if (ntile > 0) qbase = atomicAdd(qcnt, ntile);
    }
    __syncthreads();
    if (t < ntile) queue[qbase + t] = (b << 16) | t;
}

// fw MLP over updated rows: 32 upd rows/tile; xs rows 0-31 = x, 32-63 = x_prev*r^k.
// 256 threads (4 waves), ~17 KB LDS (hs aliased into xs) -> 4 blocks/CU.
__global__ __launch_bounds__(256, 4) void k_fw(
    const float* __restrict__ F, const float* __restrict__ rp_,
    const __bf16* __restrict__ wsW,
    const float* __restrict__ b1, const float* __restrict__ b2,
    const int* __restrict__ STEP, const int* __restrict__ BIDX,
    const int* __restrict__ cnt, const unsigned short* __restrict__ list,
    const int* __restrict__ qcnt, const int* __restrict__ queue,
    float* __restrict__ out) {
    __shared__ __bf16 xs[64 * D_];
    __shared__ int rows_s[32];
    __shared__ float rsc_s[32];
    __shared__ int stj[J_];
    const int t = threadIdx.x;
    const int ln = t & 15, lq = (t >> 4) & 3, wid = t >> 6;
    const int wcol = wid & 1, wrow = wid >> 1;       // wrow in {0,1}
    bf16x8 w1r[4][4], w2r[4][4];
    load_wregs(wsW, wcol, ln, lq, w1r);              // fw W1^T
    load_wregs(wsW + 16384, wcol, ln, lq, w2r);      // fw W2^T
    const float r = *rp_;
    const int qn = *qcnt;

    for (int qi = blockIdx.x; qi < qn; qi += gridDim.x) {
        const int e = queue[qi];
        const int b = e >> 16, ti = e & 0xffff;
        const int c_ = cnt[b];
        const int r0_ = ti * 32;
        __syncthreads();   // xs free from previous tile
        if (t < 32) rows_s[t] = (r0_ + t < c_) ? (int)list[b * N_ + r0_ + t] : -1;
        else if (t < 64) stj[t - 32] = STEP[BIDX[b] * J_ + (t - 32)];
        __syncthreads();
        if (t < 32) {
            const int gi = rows_s[t];
            rsc_s[t] = (gi >= 1) ? __powf(r, (float)(gi - stj[gi >> 6])) : 0.f;
        }
        __syncthreads();
        const float* Fb = F + (size_t)b * N_ * D_;
        for (int id = t; id < 64 * 16; id += 256) {
            const int rr = id >> 4, ch = id & 15;
            bf16x8 u;
            if (rr < 32) {
                const int gi = rows_s[rr];
                if (gi >= 0) {
                    const float* fr = Fb + (size_t)gi * D_ + ch * 8;
                    const float4 f0 = *(const float4*)fr, f1 = *(const float4*)(fr + 4);
                    u[0] = (__bf16)f0.x; u[1] = (__bf16)f0.y; u[2] = (__bf16)f0.z; u[3] = (__bf16)f0.w;
                    u[4] = (__bf16)f1.x; u[5] = (__bf16)f1.y; u[6] = (__bf16)f1.z; u[7] = (__bf16)f1.w;
                } else {
#pragma unroll
                    for (int j = 0; j < 8; ++j) u[j] = (__bf16)0.f;
                }
            } else {
                const int gi = rows_s[rr - 32];
                if (gi >= 1) {
                    const float s = rsc_s[rr - 32];
                    const float* fr = Fb + (size_t)(gi - 1) * D_ + ch * 8;
                    const float4 f0 = *(const float4*)fr, f1 = *(const float4*)(fr + 4);
                    u[0] = (__bf16)(f0.x * s); u[1] = (__bf16)(f0.y * s);
                    u[2] = (__bf16)(f0.z * s); u[3] = (__bf16)(f0.w * s);
                    u[4] = (__bf16)(f1.x * s); u[5] = (__bf16)(f1.y * s);
                    u[6] = (__bf16)(f1.z * s); u[7] = (__bf16)(f1.w * s);
                } else {
#pragma unroll
                    for (int j = 0; j < 8; ++j) u[j] = (__bf16)0.f;
                }
            }
            *(bf16x8*)&xs[rr * D_ + ((ch ^ (rr & 7)) << 3)] = u;
        }
        __syncthreads();
        f32x4 acc[4][2];
        gemmT(xs, w1r, wrow * 32, wrow * 32 + 16, ln, lq, acc);   // 64 rows @ W1
        __syncthreads();                                           // all xs reads done
        epiT_lds<ACT_ELU>(acc, xs, b1, wcol, wrow * 32, wrow * 32 + 16, ln, lq);  // h -> xs
        __syncthreads();
        gemmT(xs, w2r, wrow * 16, wrow * 16 + 32, ln, lq, acc);   // branch pair @ W2
        char* outc = (char*)out + (size_t)b * N_ * 512;
        const int gi = rows_s[wrow * 16 + ln];
        if (gi >= 0) {
#pragma unroll
            for (int mt = 0; mt < 4; ++mt) {
                const int cb = wcol * 64 + mt * 16 + lq * 4;
                const f32x4 bv = *(const f32x4*)&b2[cb];
                bf16x4 o;
#pragma unroll
                for (int rr2 = 0; rr2 < 4; ++rr2)
                    o[rr2] = (__bf16)(acc[mt][0][rr2] + acc[mt][1][rr2] + 2.f * bv[rr2]);
                *(bf16x4*)(outc + (size_t)gi * 512 + cb * 2) = o;  // cand bf16 scratch
            }
        }
    }
}

// head: z = MLP_zj(mixed) for valid jobs; z written bf16 into out rows' first 256B
__global__ __launch_bounds__(256, 2) void k_head(
    const float* __restrict__ F, const float* __restrict__ rp_,
    const __bf16* __restrict__ wsW,
    const float* __restrict__ zb1, const float* __restrict__ zb2,
    const int* __restrict__ STEP, const int* __restrict__ ENDB,
    const int* __restrict__ BIDX, const float* __restrict__ Sbuf,
    const int* __restrict__ nvalid, float* __restrict__ out) {
    __shared__ __bf16 wlds[2 * 16384];
    __shared__ __bf16 xs[64 * D_];
    __shared__ __bf16 hs[64 * D_];
    __shared__ int rows_s[64];
    __shared__ int stp[J_];
    const int b = blockIdx.x;
    const int t = threadIdx.x;
    const int lane = t & 63, wid = t >> 6;
    const TCtx tc{wid >> 1, wid & 1, lane & 15, lane >> 4};
#pragma unroll
    for (int i = 0; i < 16; ++i) {
        const int off = (i * 256 + t) * 8;
        *(bf16x8*)&wlds[off] = *(const bf16x8*)&wsW[4 * 16384 + off];   // zj W1, W2
    }
    const int bi = BIDX[b];
    if (t < J_) {
        const int s = STEP[bi * J_ + t];
        stp[t] = s;
        rows_s[t] = (s <= ENDB[bi * J_ + t]) ? t : -1;
    } else if (t < 64) {
        rows_s[t] = -1;
    }
    __syncthreads();
    const float n_ = (float)nvalid[b];
    const float r = *rp_;
    const float inv = (n_ > 0.f) ? 1.f / n_ : 0.f;
    const float* Fb = F + (size_t)b * N_ * D_;

    for (int id = t; id < 64 * 16; id += 256) {
        const int row = id >> 4, ch = id & 15;
        bf16x8 u;
        if (row < J_ && rows_s[row] >= 0) {
            const float4 c0 = *(const float4*)(Fb + (size_t)stp[row] * D_ + ch * 8);
            const float4 c1 = *(const float4*)(Fb + (size_t)stp[row] * D_ + ch * 8 + 4);
            const float4 s0 = *(const float4*)(Sbuf + b * D_ + ch * 8);
            const float4 s1 = *(const float4*)(Sbuf + b * D_ + ch * 8 + 4);
            u[0] = (__bf16)((c0.x + r * (s0.x - c0.x)) * inv);
            u[1] = (__bf16)((c0.y + r * (s0.y - c0.y)) * inv);
            u[2] = (__bf16)((c0.z + r * (s0.z - c0.z)) * inv);
            u[3] = (__bf16)((c0.w + r * (s0.w - c0.w)) * inv);
            u[4] = (__bf16)((c1.x + r * (s1.x - c1.x)) * inv);
            u[5] = (__bf16)((c1.y + r * (s1.y - c1.y)) * inv);
            u[6] = (__bf16)((c1.z + r * (s1.z - c1.z)) * inv);
            u[7] = (__bf16)((c1.w + r * (s1.w - c1.w)) * inv);
        } else {
#pragma unroll
            for (int j = 0; j < 8; ++j) u[j] = (__bf16)0.f;
        }
        *(bf16x8*)&xs[row * D_ + ((ch ^ (row & 7)) << 3)] = u;
    }
    __syncthreads();
    f32x4 acc[2][4];
    mfma_gemm(xs, wlds, tc, acc);
    epi_lds<ACT_ELU>(acc, hs, zb1, 1.f, tc);
    __syncthreads();
    mfma_gemm(hs, wlds + 16384, tc, acc);
    char* outc = (char*)out + (size_t)b * N_ * 512;
#pragma unroll
    for (int n = 0; n < 4; ++n) {
        const int gcol = tc.wc * 64 + n * 16 + tc.ln;
        const float bb = zb2[gcol];
#pragma unroll
        for (int m = 0; m < 2; ++m)
#pragma unroll
            for (int rg = 0; rg < 4; ++rg) {
                const int row = tc.wr * 32 + m * 16 + tc.lq * 4 + rg;
                const int gi = rows_s[row];
                if (gi >= 0)
                    *(__bf16*)(outc + (size_t)gi * 512 + gcol * 2) = (__bf16)(acc[m][n][rg] + bb);
            }
    }
}

// pr MLP over ALL rows, 64-row slots, 256 threads, hs aliased into xs (~17 KB LDS)
__global__ __launch_bounds__(256, 4) void k_pr(
    const float* __restrict__ F, const unsigned char* __restrict__ flag,
    const __bf16* __restrict__ wsW,
    const float* __restrict__ pb1, const float* __restrict__ pb2,
    float* __restrict__ out) {
    __shared__ __bf16 xs[64 * D_];
    __shared__ unsigned char flg[64];
    const int t = threadIdx.x;
    const int ln = t & 15, lq = (t >> 4) & 3, wid = t >> 6;
    const int wcol = wid & 1, wrow = wid >> 1;       // wrow in {0,1}
    bf16x8 w1r[4][4], w2r[4][4];
    load_wregs(wsW + 2 * 16384, wcol, ln, lq, w1r);  // pr W1^T
    load_wregs(wsW + 3 * 16384, wcol, ln, lq, w2r);  // pr W2^T

    for (int slot = blockIdx.x; slot < B_ * 32; slot += gridDim.x) {
        const int b = slot & 63, ti = slot >> 6;
        const int row0 = ti * 64;
        __syncthreads();   // xs/flg free from previous slot
        if (t < 64) flg[t] = flag[b * N_ + row0 + t];
        __syncthreads();
        const float* Fb = F + ((size_t)b * N_ + row0) * D_;
        const char* candb = (const char*)out + ((size_t)b * N_ + row0) * 512;
        for (int id = t; id < 64 * 16; id += 256) {
            const int rr = id >> 4, ch = id & 15;
            bf16x8 u;
            if (flg[rr]) {
                u = *(const bf16x8*)(candb + (size_t)rr * 512 + ch * 16);
            } else {
                const float* fr = Fb + (size_t)rr * D_ + ch * 8;
                const float4 f0 = *(const float4*)fr, f1 = *(const float4*)(fr + 4);
                u[0] = (__bf16)f0.x; u[1] = (__bf16)f0.y; u[2] = (__bf16)f0.z; u[3] = (__bf16)f0.w;
                u[4] = (__bf16)f1.x; u[5] = (__bf16)f1.y; u[6] = (__bf16)f1.z; u[7] = (__bf16)f1.w;
            }
            *(bf16x8*)&xs[rr * D_ + ((ch ^ (rr & 7)) << 3)] = u;
        }
        __syncthreads();
        f32x4 acc[4][2];
        gemmT(xs, w1r, wrow * 32, wrow * 32 + 16, ln, lq, acc);   // @ P1
        __syncthreads();                                           // all xs reads done
        epiT_lds<ACT_ELU>(acc, xs, pb1, wcol, wrow * 32, wrow * 32 + 16, ln, lq);
        __syncthreads();
        gemmT(xs, w2r, wrow * 32, wrow * 32 + 16, ln, lq, acc);   // @ P2
        float* outb = out + ((size_t)b * N_ + row0) * D_;
#pragma unroll
        for (int mt = 0; mt < 4; ++mt) {
            const int cb = wcol * 64 + mt * 16 + lq * 4;
            const f32x4 bv = *(const f32x4*)&pb2[cb];
#pragma unroll
            for (int nt = 0; nt < 2; ++nt) {
                const int jr = wrow * 32 + nt * 16 + ln;
                f32x4 o;
#pragma unroll
                for (int rr2 = 0; rr2 < 4; ++rr2)
                    o[rr2] = apply_act<ACT_LEAKY>(acc[mt][nt][rr2] + bv[rr2]);
                *(f32x4*)&outb[(size_t)jr * D_ + cb] = o;
            }
        }
    }
}

extern "C" void kernel_launch(void* const* d_in, const int* in_sizes, int n_in,
                              void* d_out, int out_size, void* d_ws, size_t ws_size,
                              hipStream_t stream) {
    const float* F    = (const float*)d_in[0];
    const float* rp   = (const float*)d_in[1];
    const int*  STEP  = (const int*)d_in[2];
    const int*  ENDB  = (const int*)d_in[3];
    const int*  BIDX  = (const int*)d_in[5];
    const float* fwW1 = (const float*)d_in[6];
    const float* fwb1 = (const float*)d_in[7];
    const float* fwW2 = (const float*)d_in[8];
    const float* fwb2 = (const float*)d_in[9];
    const float* zjW1 = (const float*)d_in[10];
    const float* zjb1 = (const float*)d_in[11];
    const float* zjW2 = (const float*)d_in[12];
    const float* zjb2 = (const float*)d_in[13];
    const float* prW1 = (const float*)d_in[14];
    const float* prb1 = (const float*)d_in[15];
    const float* prW2 = (const float*)d_in[16];
    const float* prb2 = (const float*)d_in[17];
    float* out = (float*)d_out;

    char* ws = (char*)d_ws;
    __bf16* wsW          = (__bf16*)ws;                     // 393216 B
    float* Sbuf          = (float*)(ws + 393216);           // 32768 B
    int* nvalid          = (int*)(ws + 425984);             // 256 B
    int* cnt_upd         = (int*)(ws + 426240);             // 256 B
    unsigned short* lupd = (unsigned short*)(ws + 426496);  // 262144 B
    unsigned char* flag  = (unsigned char*)(ws + 688640);   // 131072 B
    int* qcnt            = (int*)(ws + 819712);             // 256 B
    int* queue           = (int*)(ws + 819968);             // 16384 B

    hipMemsetAsync(qcnt, 0, 4, stream);
    hipLaunchKernelGGL(k_prep, dim3(70), dim3(256), 0, stream,
                       fwW1, fwW2, prW1, prW2, zjW1, zjW2, wsW,
                       F, STEP, ENDB, BIDX, Sbuf, nvalid, cnt_upd, lupd, flag, qcnt, queue);
    hipLaunchKernelGGL(k_head, dim3(B_), dim3(256), 0, stream,
                       F, rp, wsW, zjb1, zjb2, STEP, ENDB, BIDX, Sbuf, nvalid, out);
    hipLaunchKernelGGL(k_fw, dim3(1024), dim3(256), 0, stream,
                       F, rp, wsW, fwb1, fwb2, STEP, BIDX, cnt_upd, lupd, qcnt, queue, out);
    hipLaunchKernelGGL(k_pr, dim3(1024), dim3(256), 0, stream,
                       F, flag, wsW, prb1, prb2, out);
}

// Round 7
// 83.452 us; speedup vs baseline: 2.3258x; 2.3258x over previous
//
#include <hip/hip_runtime.h>

#define B_ 64
#define N_ 2048
#define J_ 32
#define D_ 128
#define NEG_SLOPE_ 0.2f

typedef __attribute__((ext_vector_type(4))) float f32x4;
typedef __attribute__((ext_vector_type(8))) __bf16 bf16x8;
typedef __attribute__((ext_vector_type(4))) __bf16 bf16x4;

#define ACT_NONE 0
#define ACT_ELU 1
#define ACT_LEAKY 2

template<int ACT>
__device__ __forceinline__ float apply_act(float v) {
    if constexpr (ACT == ACT_ELU)        return v > 0.f ? v : __expf(v) - 1.f;
    else if constexpr (ACT == ACT_LEAKY) return v >= 0.f ? v : NEG_SLOPE_ * v;
    else return v;
}

// read one bf16x8 fragment from swizzled row-major [row][128] storage
__device__ __forceinline__ bf16x8 frag_ld(const __bf16* src, int row, int kc) {
    return *(const bf16x8*)&src[row * D_ + ((kc ^ (row & 7)) << 3)];
}

// preload this wave's 32-col W^T strip into registers: 8 frags (32 VGPR)
__device__ __forceinline__ void load_wregs2(const __bf16* __restrict__ wmat,
                                            int wst, int ln, int lq, bf16x8 wr_[4][2]) {
#pragma unroll
    for (int ks = 0; ks < 4; ++ks)
#pragma unroll
        for (int mt = 0; mt < 2; ++mt)
            wr_[ks][mt] = frag_ld(wmat, wst * 32 + mt * 16 + ln, ks * 4 + lq);
}

// strip GEMM: 64 LDS rows @ W^T strip (regs).
// lane holds out[row = nt*16 + (l&15)][cols = wst*32 + mt*16 + lq*4 .. +3]
__device__ __forceinline__ void gemmS(const __bf16* xb, const bf16x8 wr_[4][2],
                                      int ln, int lq, f32x4 acc[2][4]) {
    const f32x4 z = {0.f, 0.f, 0.f, 0.f};
#pragma unroll
    for (int mt = 0; mt < 2; ++mt)
#pragma unroll
        for (int nt = 0; nt < 4; ++nt) acc[mt][nt] = z;
#pragma unroll
    for (int ks = 0; ks < 4; ++ks) {
        const int kc = ks * 4 + lq;
        bf16x8 b[4];
#pragma unroll
        for (int nt = 0; nt < 4; ++nt) b[nt] = frag_ld(xb, nt * 16 + ln, kc);
#pragma unroll
        for (int mt = 0; mt < 2; ++mt)
#pragma unroll
            for (int nt = 0; nt < 4; ++nt)
                acc[mt][nt] = __builtin_amdgcn_mfma_f32_16x16x32_bf16(wr_[ks][mt], b[nt], acc[mt][nt], 0, 0, 0);
    }
}

// strip epilogue: act(acc + bias) -> swizzled LDS rows, bf16x4 per store
template<int ACT>
__device__ __forceinline__ void epiS_lds(const f32x4 acc[2][4], __bf16* dst,
                                         const float* __restrict__ bias,
                                         int wst, int ln, int lq) {
#pragma unroll
    for (int mt = 0; mt < 2; ++mt) {
        const int cb = wst * 32 + mt * 16 + lq * 4;
        const f32x4 bv = *(const f32x4*)&bias[cb];
#pragma unroll
        for (int nt = 0; nt < 4; ++nt) {
            const int jr = nt * 16 + ln;
            bf16x4 o;
#pragma unroll
            for (int r = 0; r < 4; ++r)
                o[r] = (__bf16)apply_act<ACT>(acc[mt][nt][r] + bv[r]);
            *(bf16x4*)&dst[jr * D_ + (((cb >> 3) ^ (jr & 7)) << 3) + (cb & 7)] = o;
        }
    }
}

// ---------- legacy standard-orientation core (k_head only) ----------
struct TCtx { int wr, wc, ln, lq; };

__device__ __forceinline__ void mfma_gemm(const __bf16* __restrict__ xb,
                                          const __bf16* __restrict__ wb,
                                          const TCtx& c, f32x4 acc[2][4]) {
    const f32x4 zero = {0.f, 0.f, 0.f, 0.f};
#pragma unroll
    for (int m = 0; m < 2; ++m)
#pragma unroll
        for (int n = 0; n < 4; ++n) acc[m][n] = zero;
    const int r0 = c.wr * 32 + c.ln;
    const int r1 = r0 + 16;
#pragma unroll
    for (int ks = 0; ks < 4; ++ks) {
        const int kc = ks * 4 + c.lq;
        const bf16x8 a0 = frag_ld(xb, r0, kc);
        const bf16x8 a1 = frag_ld(xb, r1, kc);
#pragma unroll
        for (int n = 0; n < 4; ++n) {
            const int nr = c.wc * 64 + n * 16 + c.ln;
            const bf16x8 bv = frag_ld(wb, nr, kc);
            acc[0][n] = __builtin_amdgcn_mfma_f32_16x16x32_bf16(a0, bv, acc[0][n], 0, 0, 0);
            acc[1][n] = __builtin_amdgcn_mfma_f32_16x16x32_bf16(a1, bv, acc[1][n], 0, 0, 0);
        }
    }
}

template<int ACT>
__device__ __forceinline__ void epi_lds(const f32x4 acc[2][4], __bf16* dst,
                                        const float* __restrict__ bias, float bscale,
                                        const TCtx& c) {
#pragma unroll
    for (int n = 0; n < 4; ++n) {
        const int gcol = c.wc * 64 + n * 16 + c.ln;
        const float bb = bscale * bias[gcol];
        const int cc = gcol >> 3, co = gcol & 7;
#pragma unroll
        for (int m = 0; m < 2; ++m) {
#pragma unroll
            for (int rg = 0; rg < 4; ++rg) {
                const int grow = c.wr * 32 + m * 16 + c.lq * 4 + rg;
                dst[grow * D_ + ((cc ^ (grow & 7)) << 3) + co] =
                    (__bf16)apply_act<ACT>(acc[m][n][rg] + bb);
            }
        }
    }
}

// merged prep: blocks 0-5 convert W fp32 -> WT bf16 swizzled; blocks 6-69 per-batch prep
__global__ __launch_bounds__(256) void k_prep(
    const float* __restrict__ w0, const float* __restrict__ w1,
    const float* __restrict__ w2, const float* __restrict__ w3,
    const float* __restrict__ w4, const float* __restrict__ w5,
    __bf16* __restrict__ wdst,
    const float* __restrict__ F, const int* __restrict__ STEP,
    const int* __restrict__ ENDB, const int* __restrict__ BIDX,
    float* __restrict__ Sbuf, int* __restrict__ nvalid, int* __restrict__ cnt_upd,
    unsigned short* __restrict__ lupd, unsigned char* __restrict__ flag,
    int* __restrict__ qcnt, int* __restrict__ queue) {
    const int t = threadIdx.x;
    if (blockIdx.x < 6) {
        const float* src;
        switch (blockIdx.x) {
            case 0: src = w0; break; case 1: src = w1; break; case 2: src = w2; break;
            case 3: src = w3; break; case 4: src = w4; break; default: src = w5; break;
        }
        __bf16* d = wdst + (size_t)blockIdx.x * D_ * D_;
        for (int id = t; id < D_ * 16; id += 256) {
            const int n = id >> 4, ch = id & 15;
            bf16x8 u;
#pragma unroll
            for (int j = 0; j < 8; ++j) u[j] = (__bf16)src[(ch * 8 + j) * D_ + n];
            *(bf16x8*)&d[n * D_ + ((ch ^ (n & 7)) << 3)] = u;
        }
        return;
    }
    const int b = blockIdx.x - 6;
    __shared__ int steps_s[J_];
    __shared__ int valid_s[J_];
    __shared__ int cu, nv, qbase;
    const int bi = BIDX[b];
    if (t == 0) { cu = 0; nv = 0; }
    __syncthreads();
    if (t < J_) {
        const int s = STEP[bi * J_ + t];
        const int e = ENDB[bi * J_ + t];
        steps_s[t] = s;
        const int v = (s <= e) ? 1 : 0;
        valid_s[t] = v;
        if (v) atomicAdd(&nv, 1);
    }
    __syncthreads();
    if (t < D_) {
        float acc = 0.f;
        for (int j = 0; j < J_; ++j)
            if (valid_s[j]) acc += F[((size_t)b * N_ + steps_s[j]) * D_ + t];
        Sbuf[b * D_ + t] = acc;
    }
    for (int i = t; i < N_; i += blockDim.x) {
        const bool head = (i < J_) && valid_s[i];
        unsigned char fl = 0;
        if (head) {
            fl = 1;
        } else if (i > steps_s[i >> 6]) {
            const int s = atomicAdd(&cu, 1);
            lupd[b * N_ + s] = (unsigned short)i;
            fl = 1;
        }
        flag[b * N_ + i] = fl;
    }
    __syncthreads();
    const int ntile = (cu + 31) >> 5;          // 32-row tiles
    if (t == 0) {
        nvalid[b] = nv;
        cnt_upd[b] = cu;
        if (ntile > 0) qbase = atomicAdd(qcnt, ntile);
    }
    __syncthreads();
    if (t < ntile) queue[qbase + t] = (b << 16) | t;
}

// fw MLP over updated rows: one 32-upd-row tile per block.
// xs rows 0-31 = x, 32-63 = x_prev*r^k; GEMM2 chains both row-halves into one acc.
__global__ __launch_bounds__(256, 2) void k_fw(
    const float* __restrict__ F, const float* __restrict__ rp_,
    const __bf16* __restrict__ wsW,
    const float* __restrict__ b1, const float* __restrict__ b2,
    const int* __restrict__ STEP, const int* __restrict__ BIDX,
    const int* __restrict__ cnt, const unsigned short* __restrict__ list,
    const int* __restrict__ qcnt, const int* __restrict__ queue,
    float* __restrict__ out) {
    __shared__ __bf16 xs[64 * D_];
    __shared__ __bf16 hs[64 * D_];
    __shared__ int rows_s[32];
    __shared__ float rsc_s[32];
    __shared__ int stj[J_];
    const int qi = blockIdx.x;
    if (qi >= *qcnt) return;
    const int t = threadIdx.x;
    const int lane = t & 63, wst = t >> 6;
    const int ln = lane & 15, lq = lane >> 4;
    bf16x8 w1r[4][2], w2r[4][2];
    load_wregs2(wsW, wst, ln, lq, w1r);              // fw W1^T strip
    load_wregs2(wsW + 16384, wst, ln, lq, w2r);      // fw W2^T strip
    const float r = *rp_;

    const int e = queue[qi];
    const int b = e >> 16, ti = e & 0xffff;
    const int c_ = cnt[b];
    const int r0_ = ti * 32;
    if (t < 32) rows_s[t] = (r0_ + t < c_) ? (int)list[b * N_ + r0_ + t] : -1;
    else if (t < 64) stj[t - 32] = STEP[BIDX[b] * J_ + (t - 32)];
    __syncthreads();
    if (t < 32) {
        const int gi = rows_s[t];
        rsc_s[t] = (gi >= 1) ? __powf(r, (float)(gi - stj[gi >> 6])) : 0.f;
    }
    __syncthreads();
    const float* Fb = F + (size_t)b * N_ * D_;
    for (int id = t; id < 64 * 16; id += 256) {
        const int rr = id >> 4, ch = id & 15;
        bf16x8 u;
        if (rr < 32) {
            const int gi = rows_s[rr];
            if (gi >= 0) {
                const float* fr = Fb + (size_t)gi * D_ + ch * 8;
                const float4 f0 = *(const float4*)fr, f1 = *(const float4*)(fr + 4);
                u[0] = (__bf16)f0.x; u[1] = (__bf16)f0.y; u[2] = (__bf16)f0.z; u[3] = (__bf16)f0.w;
                u[4] = (__bf16)f1.x; u[5] = (__bf16)f1.y; u[6] = (__bf16)f1.z; u[7] = (__bf16)f1.w;
            } else {
#pragma unroll
                for (int j = 0; j < 8; ++j) u[j] = (__bf16)0.f;
            }
        } else {
            const int gi = rows_s[rr - 32];
            if (gi >= 1) {
                const float s = rsc_s[rr - 32];
                const float* fr = Fb + (size_t)(gi - 1) * D_ + ch * 8;
                const float4 f0 = *(const float4*)fr, f1 = *(const float4*)(fr + 4);
                u[0] = (__bf16)(f0.x * s); u[1] = (__bf16)(f0.y * s);
                u[2] = (__bf16)(f0.z * s); u[3] = (__bf16)(f0.w * s);
                u[4] = (__bf16)(f1.x * s); u[5] = (__bf16)(f1.y * s);
                u[6] = (__bf16)(f1.z * s); u[7] = (__bf16)(f1.w * s);
            } else {
#pragma unroll
                for (int j = 0; j < 8; ++j) u[j] = (__bf16)0.f;
            }
        }
        *(bf16x8*)&xs[rr * D_ + ((ch ^ (rr & 7)) << 3)] = u;
    }
    __syncthreads();
    f32x4 acc[2][4];
    gemmS(xs, w1r, ln, lq, acc);                     // h = elu(x|xprev @ W1 + b1)
    epiS_lds<ACT_ELU>(acc, hs, b1, wst, ln, lq);     // -> hs (64 rows)
    __syncthreads();
    // GEMM2: cand[i] = h[i]@W2 + h[i+32]@W2 + 2*b2 (chain both halves into one acc)
    f32x4 a2[2][2];
    const f32x4 z = {0.f, 0.f, 0.f, 0.f};
#pragma unroll
    for (int mt = 0; mt < 2; ++mt) { a2[mt][0] = z; a2[mt][1] = z; }
#pragma unroll
    for (int ks = 0; ks < 4; ++ks) {
        const int kc = ks * 4 + lq;
        const bf16x8 bl0 = frag_ld(hs, ln, kc);
        const bf16x8 bl1 = frag_ld(hs, 16 + ln, kc);
        const bf16x8 bh0 = frag_ld(hs, 32 + ln, kc);
        const bf16x8 bh1 = frag_ld(hs, 48 + ln, kc);
#pragma unroll
        for (int mt = 0; mt < 2; ++mt) {
            a2[mt][0] = __builtin_amdgcn_mfma_f32_16x16x32_bf16(w2r[ks][mt], bl0, a2[mt][0], 0, 0, 0);
            a2[mt][0] = __builtin_amdgcn_mfma_f32_16x16x32_bf16(w2r[ks][mt], bh0, a2[mt][0], 0, 0, 0);
            a2[mt][1] = __builtin_amdgcn_mfma_f32_16x16x32_bf16(w2r[ks][mt], bl1, a2[mt][1], 0, 0, 0);
            a2[mt][1] = __builtin_amdgcn_mfma_f32_16x16x32_bf16(w2r[ks][mt], bh1, a2[mt][1], 0, 0, 0);
        }
    }
    char* outc = (char*)out + (size_t)b * N_ * 512;
#pragma unroll
    for (int nt = 0; nt < 2; ++nt) {
        const int gi = rows_s[nt * 16 + ln];
        if (gi < 0) continue;
#pragma unroll
        for (int mt = 0; mt < 2; ++mt) {
            const int cb = wst * 32 + mt * 16 + lq * 4;
            const f32x4 bv = *(const f32x4*)&b2[cb];
            bf16x4 o;
#pragma unroll
            for (int rr2 = 0; rr2 < 4; ++rr2)
                o[rr2] = (__bf16)(a2[mt][nt][rr2] + 2.f * bv[rr2]);
            *(bf16x4*)(outc + (size_t)gi * 512 + cb * 2) = o;   // cand bf16 scratch
        }
    }
}

// head: z = MLP_zj(mixed) for valid jobs; z written bf16 into out rows' first 256B
__global__ __launch_bounds__(256, 2) void k_head(
    const float* __restrict__ F, const float* __restrict__ rp_,
    const __bf16* __restrict__ wsW,
    const float* __restrict__ zb1, const float* __restrict__ zb2,
    const int* __restrict__ STEP, const int* __restrict__ ENDB,
    const int* __restrict__ BIDX, const float* __restrict__ Sbuf,
    const int* __restrict__ nvalid, float* __restrict__ out) {
    __shared__ __bf16 wlds[2 * 16384];
    __shared__ __bf16 xs[64 * D_];
    __shared__ __bf16 hs[64 * D_];
    __shared__ int rows_s[64];
    __shared__ int stp[J_];
    const int b = blockIdx.x;
    const int t = threadIdx.x;
    const int lane = t & 63, wid = t >> 6;
    const TCtx tc{wid >> 1, wid & 1, lane & 15, lane >> 4};
#pragma unroll
    for (int i = 0; i < 16; ++i) {
        const int off = (i * 256 + t) * 8;
        *(bf16x8*)&wlds[off] = *(const bf16x8*)&wsW[4 * 16384 + off];   // zj W1, W2
    }
    const int bi = BIDX[b];
    if (t < J_) {
        const int s = STEP[bi * J_ + t];
        stp[t] = s;
        rows_s[t] = (s <= ENDB[bi * J_ + t]) ? t : -1;
    } else if (t < 64) {
        rows_s[t] = -1;
    }
    __syncthreads();
    const float n_ = (float)nvalid[b];
    const float r = *rp_;
    const float inv = (n_ > 0.f) ? 1.f / n_ : 0.f;
    const float* Fb = F + (size_t)b * N_ * D_;

    for (int id = t; id < 64 * 16; id += 256) {
        const int row = id >> 4, ch = id & 15;
        bf16x8 u;
        if (row < J_ && rows_s[row] >= 0) {
            const float4 c0 = *(const float4*)(Fb + (size_t)stp[row] * D_ + ch * 8);
            const float4 c1 = *(const float4*)(Fb + (size_t)stp[row] * D_ + ch * 8 + 4);
            const float4 s0 = *(const float4*)(Sbuf + b * D_ + ch * 8);
            const float4 s1 = *(const float4*)(Sbuf + b * D_ + ch * 8 + 4);
            u[0] = (__bf16)((c0.x + r * (s0.x - c0.x)) * inv);
            u[1] = (__bf16)((c0.y + r * (s0.y - c0.y)) * inv);
            u[2] = (__bf16)((c0.z + r * (s0.z - c0.z)) * inv);
            u[3] = (__bf16)((c0.w + r * (s0.w - c0.w)) * inv);
            u[4] = (__bf16)((c1.x + r * (s1.x - c1.x)) * inv);
            u[5] = (__bf16)((c1.y + r * (s1.y - c1.y)) * inv);
            u[6] = (__bf16)((c1.z + r * (s1.z - c1.z)) * inv);
            u[7] = (__bf16)((c1.w + r * (s1.w - c1.w)) * inv);
        } else {
#pragma unroll
            for (int j = 0; j < 8; ++j) u[j] = (__bf16)0.f;
        }
        *(bf16x8*)&xs[row * D_ + ((ch ^ (row & 7)) << 3)] = u;
    }
    __syncthreads();
    f32x4 acc[2][4];
    mfma_gemm(xs, wlds, tc, acc);
    epi_lds<ACT_ELU>(acc, hs, zb1, 1.f, tc);
    __syncthreads();
    mfma_gemm(hs, wlds + 16384, tc, acc);
    char* outc = (char*)out + (size_t)b * N_ * 512;
#pragma unroll
    for (int n = 0; n < 4; ++n) {
        const int gcol = tc.wc * 64 + n * 16 + tc.ln;
        const float bb = zb2[gcol];
#pragma unroll
        for (int m = 0; m < 2; ++m)
#pragma unroll
            for (int rg = 0; rg < 4; ++rg) {
                const int row = tc.wr * 32 + m * 16 + tc.lq * 4 + rg;
                const int gi = rows_s[row];
                if (gi >= 0)
                    *(__bf16*)(outc + (size_t)gi * 512 + gcol * 2) = (__bf16)(acc[m][n][rg] + bb);
            }
    }
}

// pr MLP over ALL rows: one 64-row slot per block, W strips in registers
__global__ __launch_bounds__(256, 2) void k_pr(
    const float* __restrict__ F, const unsigned char* __restrict__ flag,
    const __bf16* __restrict__ wsW,
    const float* __restrict__ pb1, const float* __restrict__ pb2,
    float* __restrict__ out) {
    __shared__ __bf16 xs[64 * D_];
    __shared__ __bf16 hs[64 * D_];
    __shared__ unsigned char flg[64];
    const int t = threadIdx.x;
    const int lane = t & 63, wst = t >> 6;
    const int ln = lane & 15, lq = lane >> 4;
    bf16x8 w1r[4][2], w2r[4][2];
    load_wregs2(wsW + 2 * 16384, wst, ln, lq, w1r);  // pr W1^T strip
    load_wregs2(wsW + 3 * 16384, wst, ln, lq, w2r);  // pr W2^T strip

    const int slot = blockIdx.x;
    const int b = slot >> 5, ti = slot & 31;
    const int row0 = ti * 64;
    if (t < 64) flg[t] = flag[b * N_ + row0 + t];
    __syncthreads();
    const float* Fb = F + ((size_t)b * N_ + row0) * D_;
    const char* candb = (const char*)out + ((size_t)b * N_ + row0) * 512;
    for (int id = t; id < 64 * 16; id += 256) {
        const int rr = id >> 4, ch = id & 15;
        bf16x8 u;
        if (flg[rr]) {
            u = *(const bf16x8*)(candb + (size_t)rr * 512 + ch * 16);
        } else {
            const float* fr = Fb + (size_t)rr * D_ + ch * 8;
            const float4 f0 = *(const float4*)fr, f1 = *(const float4*)(fr + 4);
            u[0] = (__bf16)f0.x; u[1] = (__bf16)f0.y; u[2] = (__bf16)f0.z; u[3] = (__bf16)f0.w;
            u[4] = (__bf16)f1.x; u[5] = (__bf16)f1.y; u[6] = (__bf16)f1.z; u[7] = (__bf16)f1.w;
        }
        *(bf16x8*)&xs[rr * D_ + ((ch ^ (rr & 7)) << 3)] = u;
    }
    __syncthreads();
    f32x4 acc[2][4];
    gemmS(xs, w1r, ln, lq, acc);                     // @ P1
    epiS_lds<ACT_ELU>(acc, hs, pb1, wst, ln, lq);
    __syncthreads();
    gemmS(hs, w2r, ln, lq, acc);                     // @ P2
    float* outb = out + ((size_t)b * N_ + row0) * D_;
#pragma unroll
    for (int mt = 0; mt < 2; ++mt) {
        const int cb = wst * 32 + mt * 16 + lq * 4;
        const f32x4 bv = *(const f32x4*)&pb2[cb];
#pragma unroll
        for (int nt = 0; nt < 4; ++nt) {
            const int jr = nt * 16 + ln;
            f32x4 o;
#pragma unroll
            for (int rr2 = 0; rr2 < 4; ++rr2)
                o[rr2] = apply_act<ACT_LEAKY>(acc[mt][nt][rr2] + bv[rr2]);
            *(f32x4*)&outb[(size_t)jr * D_ + cb] = o;
        }
    }
}

extern "C" void kernel_launch(void* const* d_in, const int* in_sizes, int n_in,
                              void* d_out, int out_size, void* d_ws, size_t ws_size,
                              hipStream_t stream) {
    const float* F    = (const float*)d_in[0];
    const float* rp   = (const float*)d_in[1];
    const int*  STEP  = (const int*)d_in[2];
    const int*  ENDB  = (const int*)d_in[3];
    const int*  BIDX  = (const int*)d_in[5];
    const float* fwW1 = (const float*)d_in[6];
    const float* fwb1 = (const float*)d_in[7];
    const float* fwW2 = (const float*)d_in[8];
    const float* fwb2 = (const float*)d_in[9];
    const float* zjW1 = (const float*)d_in[10];
    const float* zjb1 = (const float*)d_in[11];
    const float* zjW2 = (const float*)d_in[12];
    const float* zjb2 = (const float*)d_in[13];
    const float* prW1 = (const float*)d_in[14];
    const float* prb1 = (const float*)d_in[15];
    const float* prW2 = (const float*)d_in[16];
    const float* prb2 = (const float*)d_in[17];
    float* out = (float*)d_out;

    char* ws = (char*)d_ws;
    __bf16* wsW          = (__bf16*)ws;                     // 393216 B
    float* Sbuf          = (float*)(ws + 393216);           // 32768 B
    int* nvalid          = (int*)(ws + 425984);             // 256 B
    int* cnt_upd         = (int*)(ws + 426240);             // 256 B
    unsigned short* lupd = (unsigned short*)(ws + 426496);  // 262144 B
    unsigned char* flag  = (unsigned char*)(ws + 688640);   // 131072 B
    int* qcnt            = (int*)(ws + 819712);             // 256 B
    int* queue           = (int*)(ws + 819968);             // 16384 B

    hipMemsetAsync(qcnt, 0, 4, stream);
    hipLaunchKernelGGL(k_prep, dim3(70), dim3(256), 0, stream,
                       fwW1, fwW2, prW1, prW2, zjW1, zjW2, wsW,
                       F, STEP, ENDB, BIDX, Sbuf, nvalid, cnt_upd, lupd, flag, qcnt, queue);
    hipLaunchKernelGGL(k_head, dim3(B_), dim3(256), 0, stream,
                       F, rp, wsW, zjb1, zjb2, STEP, ENDB, BIDX, Sbuf, nvalid, out);
    hipLaunchKernelGGL(k_fw, dim3(2048), dim3(256), 0, stream,
                       F, rp, wsW, fwb1, fwb2, STEP, BIDX, cnt_upd, lupd, qcnt, queue, out);
    hipLaunchKernelGGL(k_pr, dim3(2048), dim3(256), 0, stream,
                       F, flag, wsW, prb1, prb2, out);
}

// Round 8
// 77.014 us; speedup vs baseline: 2.5202x; 1.0836x over previous
//
#include <hip/hip_runtime.h>

#define B_ 64
#define N_ 2048
#define J_ 32
#define D_ 128
#define NEG_SLOPE_ 0.2f

typedef __attribute__((ext_vector_type(4))) float f32x4;
typedef __attribute__((ext_vector_type(8))) __bf16 bf16x8;
typedef __attribute__((ext_vector_type(4))) __bf16 bf16x4;

#define ACT_NONE 0
#define ACT_ELU 1
#define ACT_LEAKY 2

template<int ACT>
__device__ __forceinline__ float apply_act(float v) {
    if constexpr (ACT == ACT_ELU)        return v > 0.f ? v : __expf(v) - 1.f;
    else if constexpr (ACT == ACT_LEAKY) return v >= 0.f ? v : NEG_SLOPE_ * v;
    else return v;
}

// read one bf16x8 fragment from swizzled row-major [row][128] storage
__device__ __forceinline__ bf16x8 frag_ld(const __bf16* src, int row, int kc) {
    return *(const bf16x8*)&src[row * D_ + ((kc ^ (row & 7)) << 3)];
}

// preload this wave's 32-col W^T strip into registers: 8 frags (32 VGPR)
__device__ __forceinline__ void load_wregs2(const __bf16* __restrict__ wmat,
                                            int wst, int ln, int lq, bf16x8 wr_[4][2]) {
#pragma unroll
    for (int ks = 0; ks < 4; ++ks)
#pragma unroll
        for (int mt = 0; mt < 2; ++mt)
            wr_[ks][mt] = frag_ld(wmat, wst * 32 + mt * 16 + ln, ks * 4 + lq);
}

// strip GEMM: 64 LDS rows @ W^T strip (regs).
// lane holds out[row = nt*16 + (l&15)][cols = wst*32 + mt*16 + lq*4 .. +3]
__device__ __forceinline__ void gemmS(const __bf16* xb, const bf16x8 wr_[4][2],
                                      int ln, int lq, f32x4 acc[2][4]) {
    const f32x4 z = {0.f, 0.f, 0.f, 0.f};
#pragma unroll
    for (int mt = 0; mt < 2; ++mt)
#pragma unroll
        for (int nt = 0; nt < 4; ++nt) acc[mt][nt] = z;
#pragma unroll
    for (int ks = 0; ks < 4; ++ks) {
        const int kc = ks * 4 + lq;
        bf16x8 b[4];
#pragma unroll
        for (int nt = 0; nt < 4; ++nt) b[nt] = frag_ld(xb, nt * 16 + ln, kc);
#pragma unroll
        for (int mt = 0; mt < 2; ++mt)
#pragma unroll
            for (int nt = 0; nt < 4; ++nt)
                acc[mt][nt] = __builtin_amdgcn_mfma_f32_16x16x32_bf16(wr_[ks][mt], b[nt], acc[mt][nt], 0, 0, 0);
    }
}

// strip epilogue: act(acc + bias) -> swizzled LDS rows, bf16x4 per store
template<int ACT>
__device__ __forceinline__ void epiS_lds(const f32x4 acc[2][4], __bf16* dst,
                                         const float* __restrict__ bias,
                                         int wst, int ln, int lq) {
#pragma unroll
    for (int mt = 0; mt < 2; ++mt) {
        const int cb = wst * 32 + mt * 16 + lq * 4;
        const f32x4 bv = *(const f32x4*)&bias[cb];
#pragma unroll
        for (int nt = 0; nt < 4; ++nt) {
            const int jr = nt * 16 + ln;
            bf16x4 o;
#pragma unroll
            for (int r = 0; r < 4; ++r)
                o[r] = (__bf16)apply_act<ACT>(acc[mt][nt][r] + bv[r]);
            *(bf16x4*)&dst[jr * D_ + (((cb >> 3) ^ (jr & 7)) << 3) + (cb & 7)] = o;
        }
    }
}

// merged prep: blocks 0-5 convert W fp32 -> WT bf16 swizzled; blocks 6-69 per-batch prep
__global__ __launch_bounds__(256) void k_prep(
    const float* __restrict__ w0, const float* __restrict__ w1,
    const float* __restrict__ w2, const float* __restrict__ w3,
    const float* __restrict__ w4, const float* __restrict__ w5,
    __bf16* __restrict__ wdst,
    const float* __restrict__ F, const int* __restrict__ STEP,
    const int* __restrict__ ENDB, const int* __restrict__ BIDX,
    float* __restrict__ Sbuf, int* __restrict__ nvalid, int* __restrict__ cnt_upd,
    unsigned short* __restrict__ lupd, unsigned char* __restrict__ flag) {
    const int t = threadIdx.x;
    if (blockIdx.x < 6) {
        const float* src;
        switch (blockIdx.x) {
            case 0: src = w0; break; case 1: src = w1; break; case 2: src = w2; break;
            case 3: src = w3; break; case 4: src = w4; break; default: src = w5; break;
        }
        __bf16* d = wdst + (size_t)blockIdx.x * D_ * D_;
        for (int id = t; id < D_ * 16; id += 256) {
            const int n = id >> 4, ch = id & 15;
            bf16x8 u;
#pragma unroll
            for (int j = 0; j < 8; ++j) u[j] = (__bf16)src[(ch * 8 + j) * D_ + n];
            *(bf16x8*)&d[n * D_ + ((ch ^ (n & 7)) << 3)] = u;
        }
        return;
    }
    const int b = blockIdx.x - 6;
    __shared__ int steps_s[J_];
    __shared__ int valid_s[J_];
    __shared__ int cu, nv;
    const int bi = BIDX[b];
    if (t == 0) { cu = 0; nv = 0; }
    __syncthreads();
    if (t < J_) {
        const int s = STEP[bi * J_ + t];
        const int e = ENDB[bi * J_ + t];
        steps_s[t] = s;
        const int v = (s <= e) ? 1 : 0;
        valid_s[t] = v;
        if (v) atomicAdd(&nv, 1);
    }
    __syncthreads();
    if (t < D_) {
        float acc = 0.f;
        for (int j = 0; j < J_; ++j)
            if (valid_s[j]) acc += F[((size_t)b * N_ + steps_s[j]) * D_ + t];
        Sbuf[b * D_ + t] = acc;
    }
    for (int i = t; i < N_; i += blockDim.x) {
        const bool head = (i < J_) && valid_s[i];
        unsigned char fl = 0;
        if (head) {
            fl = 1;
        } else if (i > steps_s[i >> 6]) {
            const int s = atomicAdd(&cu, 1);
            lupd[b * N_ + s] = (unsigned short)i;
            fl = 1;
        }
        flag[b * N_ + i] = fl;
    }
    __syncthreads();
    if (t == 0) { nvalid[b] = nv; cnt_upd[b] = cu; }
}

// merged head+fw kernel, register-strip GEMM core.
// blocks 0..63: head path (z = MLP_zj(mixed), bf16 into out scratch)
// blocks 64..: fw tiles, block = 64 + b*64 + ti, tile = 32 upd rows (early exit)
__global__ __launch_bounds__(256, 2) void k_hf(
    const float* __restrict__ F, const float* __restrict__ rp_,
    const __bf16* __restrict__ wsW,
    const float* __restrict__ zb1, const float* __restrict__ zb2,
    const float* __restrict__ b1, const float* __restrict__ b2,
    const int* __restrict__ STEP, const int* __restrict__ ENDB,
    const int* __restrict__ BIDX, const float* __restrict__ Sbuf,
    const int* __restrict__ nvalid, const int* __restrict__ cnt,
    const unsigned short* __restrict__ list, float* __restrict__ out) {
    __shared__ __bf16 xs[64 * D_];
    __shared__ __bf16 hs[64 * D_];
    __shared__ int rows_s[32];
    __shared__ float rsc_s[32];
    __shared__ int stj[J_];
    const int t = threadIdx.x;
    const int lane = t & 63, wst = t >> 6;
    const int ln = lane & 15, lq = lane >> 4;
    const int bid = blockIdx.x;

    if (bid < B_) {
        // ---------------- head path ----------------
        const int b = bid;
        bf16x8 w1r[4][2], w2r[4][2];
        load_wregs2(wsW + 4 * 16384, wst, ln, lq, w1r);   // zj W1^T strip
        load_wregs2(wsW + 5 * 16384, wst, ln, lq, w2r);   // zj W2^T strip
        const int bi = BIDX[b];
        if (t < J_) {
            const int s = STEP[bi * J_ + t];
            stj[t] = s;
            rows_s[t] = (s <= ENDB[bi * J_ + t]) ? t : -1;
        }
        __syncthreads();
        const float n_ = (float)nvalid[b];
        const float r = *rp_;
        const float inv = (n_ > 0.f) ? 1.f / n_ : 0.f;
        const float* Fb = F + (size_t)b * N_ * D_;
        for (int id = t; id < 64 * 16; id += 256) {
            const int row = id >> 4, ch = id & 15;
            bf16x8 u;
            if (row < J_ && rows_s[row] >= 0) {
                const float* cr = Fb + (size_t)stj[row] * D_ + ch * 8;
                const float4 c0 = *(const float4*)cr, c1 = *(const float4*)(cr + 4);
                const float4 s0 = *(const float4*)(Sbuf + b * D_ + ch * 8);
                const float4 s1 = *(const float4*)(Sbuf + b * D_ + ch * 8 + 4);
                u[0] = (__bf16)((c0.x + r * (s0.x - c0.x)) * inv);
                u[1] = (__bf16)((c0.y + r * (s0.y - c0.y)) * inv);
                u[2] = (__bf16)((c0.z + r * (s0.z - c0.z)) * inv);
                u[3] = (__bf16)((c0.w + r * (s0.w - c0.w)) * inv);
                u[4] = (__bf16)((c1.x + r * (s1.x - c1.x)) * inv);
                u[5] = (__bf16)((c1.y + r * (s1.y - c1.y)) * inv);
                u[6] = (__bf16)((c1.z + r * (s1.z - c1.z)) * inv);
                u[7] = (__bf16)((c1.w + r * (s1.w - c1.w)) * inv);
            } else {
#pragma unroll
                for (int j = 0; j < 8; ++j) u[j] = (__bf16)0.f;
            }
            *(bf16x8*)&xs[row * D_ + ((ch ^ (row & 7)) << 3)] = u;
        }
        __syncthreads();
        f32x4 acc[2][4];
        gemmS(xs, w1r, ln, lq, acc);                      // @ Z1 (rows 32-63 garbage, unused)
        epiS_lds<ACT_ELU>(acc, hs, zb1, wst, ln, lq);
        __syncthreads();
        gemmS(hs, w2r, ln, lq, acc);                      // @ Z2
        char* outc = (char*)out + (size_t)b * N_ * 512;
#pragma unroll
        for (int nt = 0; nt < 2; ++nt) {
            const int jr = nt * 16 + ln;
            const int gi = rows_s[jr];
            if (gi < 0) continue;
#pragma unroll
            for (int mt = 0; mt < 2; ++mt) {
                const int cb = wst * 32 + mt * 16 + lq * 4;
                const f32x4 bv = *(const f32x4*)&zb2[cb];
                bf16x4 o;
#pragma unroll
                for (int rr2 = 0; rr2 < 4; ++rr2)
                    o[rr2] = (__bf16)(acc[mt][nt][rr2] + bv[rr2]);
                *(bf16x4*)(outc + (size_t)gi * 512 + cb * 2) = o;   // z bf16 scratch
            }
        }
        return;
    }

    // ---------------- fw path ----------------
    const int idx = bid - B_;
    const int b = idx >> 6, ti = idx & 63;
    const int c_ = cnt[b];
    const int r0_ = ti * 32;
    if (r0_ >= c_) return;
    bf16x8 w1r[4][2], w2r[4][2];
    load_wregs2(wsW, wst, ln, lq, w1r);                   // fw W1^T strip
    load_wregs2(wsW + 16384, wst, ln, lq, w2r);           // fw W2^T strip
    const float r = *rp_;
    if (t < 32) rows_s[t] = (r0_ + t < c_) ? (int)list[b * N_ + r0_ + t] : -1;
    else if (t < 64) stj[t - 32] = STEP[BIDX[b] * J_ + (t - 32)];
    __syncthreads();
    if (t < 32) {
        const int gi = rows_s[t];
        rsc_s[t] = (gi >= 1) ? __powf(r, (float)(gi - stj[gi >> 6])) : 0.f;
    }
    __syncthreads();
    const float* Fb = F + (size_t)b * N_ * D_;
    for (int id = t; id < 64 * 16; id += 256) {
        const int rr = id >> 4, ch = id & 15;
        bf16x8 u;
        if (rr < 32) {
            const int gi = rows_s[rr];
            if (gi >= 0) {
                const float* fr = Fb + (size_t)gi * D_ + ch * 8;
                const float4 f0 = *(const float4*)fr, f1 = *(const float4*)(fr + 4);
                u[0] = (__bf16)f0.x; u[1] = (__bf16)f0.y; u[2] = (__bf16)f0.z; u[3] = (__bf16)f0.w;
                u[4] = (__bf16)f1.x; u[5] = (__bf16)f1.y; u[6] = (__bf16)f1.z; u[7] = (__bf16)f1.w;
            } else {
#pragma unroll
                for (int j = 0; j < 8; ++j) u[j] = (__bf16)0.f;
            }
        } else {
            const int gi = rows_s[rr - 32];
            if (gi >= 1) {
                const float s = rsc_s[rr - 32];
                const float* fr = Fb + (size_t)(gi - 1) * D_ + ch * 8;
                const float4 f0 = *(const float4*)fr, f1 = *(const float4*)(fr + 4);
                u[0] = (__bf16)(f0.x * s); u[1] = (__bf16)(f0.y * s);
                u[2] = (__bf16)(f0.z * s); u[3] = (__bf16)(f0.w * s);
                u[4] = (__bf16)(f1.x * s); u[5] = (__bf16)(f1.y * s);
                u[6] = (__bf16)(f1.z * s); u[7] = (__bf16)(f1.w * s);
            } else {
#pragma unroll
                for (int j = 0; j < 8; ++j) u[j] = (__bf16)0.f;
            }
        }
        *(bf16x8*)&xs[rr * D_ + ((ch ^ (rr & 7)) << 3)] = u;
    }
    __syncthreads();
    f32x4 acc[2][4];
    gemmS(xs, w1r, ln, lq, acc);                          // h = elu(x|xprev @ W1 + b1)
    epiS_lds<ACT_ELU>(acc, hs, b1, wst, ln, lq);          // -> hs (64 rows)
    __syncthreads();
    // GEMM2: cand[i] = h[i]@W2 + h[i+32]@W2 (chain both halves into one acc)
    f32x4 a2[2][2];
    const f32x4 z = {0.f, 0.f, 0.f, 0.f};
#pragma unroll
    for (int mt = 0; mt < 2; ++mt) { a2[mt][0] = z; a2[mt][1] = z; }
#pragma unroll
    for (int ks = 0; ks < 4; ++ks) {
        const int kc = ks * 4 + lq;
        const bf16x8 bl0 = frag_ld(hs, ln, kc);
        const bf16x8 bl1 = frag_ld(hs, 16 + ln, kc);
        const bf16x8 bh0 = frag_ld(hs, 32 + ln, kc);
        const bf16x8 bh1 = frag_ld(hs, 48 + ln, kc);
#pragma unroll
        for (int mt = 0; mt < 2; ++mt) {
            a2[mt][0] = __builtin_amdgcn_mfma_f32_16x16x32_bf16(w2r[ks][mt], bl0, a2[mt][0], 0, 0, 0);
            a2[mt][0] = __builtin_amdgcn_mfma_f32_16x16x32_bf16(w2r[ks][mt], bh0, a2[mt][0], 0, 0, 0);
            a2[mt][1] = __builtin_amdgcn_mfma_f32_16x16x32_bf16(w2r[ks][mt], bl1, a2[mt][1], 0, 0, 0);
            a2[mt][1] = __builtin_amdgcn_mfma_f32_16x16x32_bf16(w2r[ks][mt], bh1, a2[mt][1], 0, 0, 0);
        }
    }
    char* outc = (char*)out + (size_t)b * N_ * 512;
#pragma unroll
    for (int nt = 0; nt < 2; ++nt) {
        const int gi = rows_s[nt * 16 + ln];
        if (gi < 0) continue;
#pragma unroll
        for (int mt = 0; mt < 2; ++mt) {
            const int cb = wst * 32 + mt * 16 + lq * 4;
            const f32x4 bv = *(const f32x4*)&b2[cb];
            bf16x4 o;
#pragma unroll
            for (int rr2 = 0; rr2 < 4; ++rr2)
                o[rr2] = (__bf16)(a2[mt][nt][rr2] + 2.f * bv[rr2]);
            *(bf16x4*)(outc + (size_t)gi * 512 + cb * 2) = o;   // cand bf16 scratch
        }
    }
}

// pr MLP over ALL rows: one 64-row slot per block, W strips in registers
__global__ __launch_bounds__(256, 2) void k_pr(
    const float* __restrict__ F, const unsigned char* __restrict__ flag,
    const __bf16* __restrict__ wsW,
    const float* __restrict__ pb1, const float* __restrict__ pb2,
    float* __restrict__ out) {
    __shared__ __bf16 xs[64 * D_];
    __shared__ __bf16 hs[64 * D_];
    __shared__ unsigned char flg[64];
    const int t = threadIdx.x;
    const int lane = t & 63, wst = t >> 6;
    const int ln = lane & 15, lq = lane >> 4;
    bf16x8 w1r[4][2], w2r[4][2];
    load_wregs2(wsW + 2 * 16384, wst, ln, lq, w1r);   // pr W1^T strip
    load_wregs2(wsW + 3 * 16384, wst, ln, lq, w2r);   // pr W2^T strip

    const int slot = blockIdx.x;
    const int b = slot >> 5, ti = slot & 31;
    const int row0 = ti * 64;
    if (t < 64) flg[t] = flag[b * N_ + row0 + t];
    __syncthreads();
    const float* Fb = F + ((size_t)b * N_ + row0) * D_;
    const char* candb = (const char*)out + ((size_t)b * N_ + row0) * 512;
    for (int id = t; id < 64 * 16; id += 256) {
        const int rr = id >> 4, ch = id & 15;
        bf16x8 u;
        if (flg[rr]) {
            u = *(const bf16x8*)(candb + (size_t)rr * 512 + ch * 16);
        } else {
            const float* fr = Fb + (size_t)rr * D_ + ch * 8;
            const float4 f0 = *(const float4*)fr, f1 = *(const float4*)(fr + 4);
            u[0] = (__bf16)f0.x; u[1] = (__bf16)f0.y; u[2] = (__bf16)f0.z; u[3] = (__bf16)f0.w;
            u[4] = (__bf16)f1.x; u[5] = (__bf16)f1.y; u[6] = (__bf16)f1.z; u[7] = (__bf16)f1.w;
        }
        *(bf16x8*)&xs[rr * D_ + ((ch ^ (rr & 7)) << 3)] = u;
    }
    __syncthreads();
    f32x4 acc[2][4];
    gemmS(xs, w1r, ln, lq, acc);                      // @ P1
    epiS_lds<ACT_ELU>(acc, hs, pb1, wst, ln, lq);
    __syncthreads();
    gemmS(hs, w2r, ln, lq, acc);                      // @ P2
    float* outb = out + ((size_t)b * N_ + row0) * D_;
#pragma unroll
    for (int mt = 0; mt < 2; ++mt) {
        const int cb = wst * 32 + mt * 16 + lq * 4;
        const f32x4 bv = *(const f32x4*)&pb2[cb];
#pragma unroll
        for (int nt = 0; nt < 4; ++nt) {
            const int jr = nt * 16 + ln;
            f32x4 o;
#pragma unroll
            for (int rr2 = 0; rr2 < 4; ++rr2)
                o[rr2] = apply_act<ACT_LEAKY>(acc[mt][nt][rr2] + bv[rr2]);
            *(f32x4*)&outb[(size_t)jr * D_ + cb] = o;
        }
    }
}

extern "C" void kernel_launch(void* const* d_in, const int* in_sizes, int n_in,
                              void* d_out, int out_size, void* d_ws, size_t ws_size,
                              hipStream_t stream) {
    const float* F    = (const float*)d_in[0];
    const float* rp   = (const float*)d_in[1];
    const int*  STEP  = (const int*)d_in[2];
    const int*  ENDB  = (const int*)d_in[3];
    const int*  BIDX  = (const int*)d_in[5];
    const float* fwW1 = (const float*)d_in[6];
    const float* fwb1 = (const float*)d_in[7];
    const float* fwW2 = (const float*)d_in[8];
    const float* fwb2 = (const float*)d_in[9];
    const float* zjW1 = (const float*)d_in[10];
    const float* zjb1 = (const float*)d_in[11];
    const float* zjW2 = (const float*)d_in[12];
    const float* zjb2 = (const float*)d_in[13];
    const float* prW1 = (const float*)d_in[14];
    const float* prb1 = (const float*)d_in[15];
    const float* prW2 = (const float*)d_in[16];
    const float* prb2 = (const float*)d_in[17];
    float* out = (float*)d_out;

    char* ws = (char*)d_ws;
    __bf16* wsW          = (__bf16*)ws;                     // 393216 B
    float* Sbuf          = (float*)(ws + 393216);           // 32768 B
    int* nvalid          = (int*)(ws + 425984);             // 256 B
    int* cnt_upd         = (int*)(ws + 426240);             // 256 B
    unsigned short* lupd = (unsigned short*)(ws + 426496);  // 262144 B
    unsigned char* flag  = (unsigned char*)(ws + 688640);   // 131072 B

    hipLaunchKernelGGL(k_prep, dim3(70), dim3(256), 0, stream,
                       fwW1, fwW2, prW1, prW2, zjW1, zjW2, wsW,
                       F, STEP, ENDB, BIDX, Sbuf, nvalid, cnt_upd, lupd, flag);
    hipLaunchKernelGGL(k_hf, dim3(B_ + B_ * 64), dim3(256), 0, stream,
                       F, rp, wsW, zjb1, zjb2, fwb1, fwb2,
                       STEP, ENDB, BIDX, Sbuf, nvalid, cnt_upd, lupd, out);
    hipLaunchKernelGGL(k_pr, dim3(B_ * 32), dim3(256), 0, stream,
                       F, flag, wsW, prb1, prb2, out);
}